// Round 1
// baseline (264.097 us; speedup 1.0000x reference)
//
#include <hip/hip_runtime.h>

typedef __attribute__((ext_vector_type(8))) __bf16 bf16x8;
typedef __attribute__((ext_vector_type(4))) float f32x4;
typedef __attribute__((ext_vector_type(4))) int i32x4;
typedef unsigned short u16;
typedef unsigned int u32;

#define DEVI __device__ __forceinline__

constexpr int CB = 4;      // batch
constexpr int CC = 512;    // channels
constexpr int CH = 8;      // heads
constexpr int CD = 64;     // head dim
constexpr int CN = 1024;   // tokens (32*32)

DEVI u16 f2bf(float f) {
    u32 u = __builtin_bit_cast(u32, f);
    u = (u + 0x7FFFu + ((u >> 16) & 1u)) >> 16;
    return (u16)u;
}

// swizzled byte offsets: XOR bits 4-6 with row low bits (keeps 16B alignment)
DEVI int swzA(int row, int col16) {   // 256B-stride rows ([64][128] bf16), col16 = 16B unit
    return (row * 256 + col16 * 16) ^ ((row & 7) << 4);
}
DEVI int swzB(int row, int col16) {   // 128B-stride rows ([64][64] bf16)
    return (row * 128 + col16 * 16) ^ ((row & 7) << 4);
}
DEVI int swzA_s(int row, int col) {   // scalar u16 element in 256B-stride tile
    return (row * 256 + col * 2) ^ ((row & 7) << 4);
}
DEVI int swzB_s(int row, int col) {
    return (row * 128 + col * 2) ^ ((row & 7) << 4);
}

DEVI bf16x8 ldfrag(const u16* base, int byteoff) {
    const i32x4* p = reinterpret_cast<const i32x4*>(reinterpret_cast<const char*>(base) + byteoff);
    return __builtin_bit_cast(bf16x8, *p);
}
DEVI void st16(u16* base, int byteoff, i32x4 v) {
    *reinterpret_cast<i32x4*>(reinterpret_cast<char*>(base) + byteoff) = v;
}
DEVI void st2(u16* base, int byteoff, u16 v) {
    *reinterpret_cast<u16*>(reinterpret_cast<char*>(base) + byteoff) = v;
}

// ---------------------------------------------------------------------------
// Projection: Y[o,n] = sum_c W[o,c] X[c,n] + b[o], per (p in {q,k,v}, batch b)
// Writes bf16 output in BOTH [o][n] (projN) and [n][o] (projT) layouts.
// ---------------------------------------------------------------------------
__global__ __launch_bounds__(256) void mqf_proj_kernel(
    const float* __restrict__ q1, const float* __restrict__ q2, const float* __restrict__ q3,
    const float* __restrict__ Wq, const float* __restrict__ bq,
    const float* __restrict__ Wk, const float* __restrict__ bk,
    const float* __restrict__ Wv, const float* __restrict__ bv,
    u16* __restrict__ projN, u16* __restrict__ projT)
{
    __shared__ __align__(16) u16 Wt[64 * 64];   // [o][c] bf16, swizzled
    __shared__ __align__(16) u16 Xt[64 * 64];   // [n][c] bf16, swizzled
    __shared__ float Tb[64 * 65];               // [o][n] f32, padded

    const int t = threadIdx.x;
    const int w = t >> 6, l = t & 63;
    const int n0 = blockIdx.x * 64;
    const int o0 = blockIdx.y * 64;
    const int p = blockIdx.z >> 2, b = blockIdx.z & 3;

    const float* X  = (p == 0 ? q1 : p == 1 ? q2 : q3) + (size_t)b * CC * CN;
    const float* Wm = (p == 0 ? Wq : p == 1 ? Wk : Wv);
    const float* bm = (p == 0 ? bq : p == 1 ? bk : bv);
    u16* oN = projN + (size_t)p * CB * CC * CN + (size_t)b * CC * CN;
    u16* oT = projT + (size_t)p * CB * CC * CN + (size_t)b * CN * CC;

    const f32x4 fz = {0.f, 0.f, 0.f, 0.f};
    f32x4 acc[4];
    for (int s = 0; s < 4; ++s) acc[s] = fz;

    for (int c0 = 0; c0 < CC; c0 += 64) {
        __syncthreads();
        #pragma unroll
        for (int pass = 0; pass < 16; ++pass) {
            int cth = t & 63;
            int oth = (t >> 6) + pass * 4;
            float f = Wm[(size_t)(o0 + oth) * CC + c0 + cth];
            st2(Wt, swzB_s(oth, cth), f2bf(f));
            int nth = t & 63;
            int cth2 = (t >> 6) + pass * 4;
            float g = X[(size_t)(c0 + cth2) * CN + n0 + nth];
            st2(Xt, swzB_s(nth, cth2), f2bf(g));
        }
        __syncthreads();
        #pragma unroll
        for (int kk = 0; kk < 2; ++kk) {
            bf16x8 af = ldfrag(Wt, swzB(w * 16 + (l & 15), kk * 4 + (l >> 4)));
            #pragma unroll
            for (int s = 0; s < 4; ++s) {
                bf16x8 bf = ldfrag(Xt, swzB(s * 16 + (l & 15), kk * 4 + (l >> 4)));
                acc[s] = __builtin_amdgcn_mfma_f32_16x16x32_bf16(af, bf, acc[s], 0, 0, 0);
            }
        }
    }
    // bias + stash tile in LDS (f32) for the double-layout writeout
    #pragma unroll
    for (int r = 0; r < 4; ++r) {
        int orow = w * 16 + (l >> 4) * 4 + r;
        float bias = bm[o0 + orow];
        #pragma unroll
        for (int s = 0; s < 4; ++s) {
            int ncol = s * 16 + (l & 15);
            Tb[orow * 65 + ncol] = acc[s][r] + bias;
        }
    }
    __syncthreads();
    #pragma unroll
    for (int pass = 0; pass < 8; ++pass) {
        int n2 = (t & 31) * 2;
        int oo = (t >> 5) + pass * 8;
        u32 v = (u32)f2bf(Tb[oo * 65 + n2]) | ((u32)f2bf(Tb[oo * 65 + n2 + 1]) << 16);
        *reinterpret_cast<u32*>(oN + (size_t)(o0 + oo) * CN + n0 + n2) = v;
        int o2 = (t & 31) * 2;
        int nn = (t >> 5) + pass * 8;
        u32 v2 = (u32)f2bf(Tb[o2 * 65 + nn]) | ((u32)f2bf(Tb[(o2 + 1) * 65 + nn]) << 16);
        *reinterpret_cast<u32*>(oT + (size_t)(n0 + nn) * CC + o0 + o2) = v2;
    }
}

// ---------------------------------------------------------------------------
// Attention: one block = 64 query rows of one (branch, b, h).
// Q'=[a;pos] (128), K'=[bm;a] (128), V=outv (64). Flash-style online softmax
// over 16 key tiles of 64. Output written as out[d][n] f32.
// ---------------------------------------------------------------------------
__global__ __launch_bounds__(256) void mqf_attn_kernel(
    const u16* __restrict__ projN, const u16* __restrict__ projT,
    const float* __restrict__ rel_h, const float* __restrict__ rel_w,
    float* __restrict__ out)
{
    __shared__ __align__(16) u16 Qt[64 * 128];  // [n][dd] swizzled
    __shared__ __align__(16) u16 Kt[64 * 128];  // [m][dd] swizzled
    __shared__ __align__(16) u16 Vt[64 * 64];   // [d][m]  swizzled
    __shared__ __align__(16) u16 Pt[64 * 64];   // [n][m]  swizzled
    __shared__ float scale_s[64];
    __shared__ float l_s[64];

    const int t = threadIdx.x;
    const int w = t >> 6, l = t & 63;
    const int n0 = blockIdx.x * 64;
    const int b = blockIdx.y >> 3, h = blockIdx.y & 7;
    const int br = blockIdx.z;

    const int ai = br, bi = (br + 1) % 3, vi = (br + 2) % 3;
    const size_t tsz = (size_t)CB * CC * CN;
    const u16* aT = projT + ai * tsz + (size_t)b * CN * CC;  // [n][o]
    const u16* bT = projT + bi * tsz + (size_t)b * CN * CC;  // [n][o]
    const u16* vN = projN + vi * tsz + (size_t)b * CC * CN;  // [o][n]

    // ---- stage Qt: rows n0..n0+63, dd 0..127 (a | pos)
    #pragma unroll
    for (int pass = 0; pass < 2; ++pass) {
        int idx = pass * 256 + t;
        int nn = idx >> 3, g = idx & 7;
        const i32x4* src = reinterpret_cast<const i32x4*>(aT + (size_t)(n0 + nn) * CC + h * CD + g * 8);
        st16(Qt, swzA(nn, g), *src);
    }
    #pragma unroll
    for (int pass = 0; pass < 16; ++pass) {
        int nn = t & 63;
        int d = (t >> 6) + pass * 4;
        int ng = n0 + nn;
        float f = rel_h[(h * CD + d) * 32 + (ng & 31)] + rel_w[(h * CD + d) * 32 + (ng >> 5)];
        st2(Qt, swzA_s(nn, 64 + d), f2bf(f));
    }

    const f32x4 fz = {0.f, 0.f, 0.f, 0.f};
    f32x4 oacc[4];
    for (int s = 0; s < 4; ++s) oacc[s] = fz;
    float mrun[4], lrun[4];
    for (int r = 0; r < 4; ++r) { mrun[r] = -1e30f; lrun[r] = 0.f; }

    for (int m0 = 0; m0 < CN; m0 += 64) {
        __syncthreads();  // previous tile's LDS reads done
        // ---- stage Kt: [m][0:64]=bm, [m][64:128]=a
        #pragma unroll
        for (int pass = 0; pass < 4; ++pass) {
            int idx = pass * 256 + t;
            int mm = idx >> 4, g = idx & 15;
            const u16* sp = (g < 8)
                ? (bT + (size_t)(m0 + mm) * CC + h * CD + g * 8)
                : (aT + (size_t)(m0 + mm) * CC + h * CD + (g - 8) * 8);
            st16(Kt, swzA(mm, g), *reinterpret_cast<const i32x4*>(sp));
        }
        // ---- stage Vt: [d][m]
        #pragma unroll
        for (int pass = 0; pass < 2; ++pass) {
            int idx = pass * 256 + t;
            int dd = idx >> 3, g = idx & 7;
            const i32x4* src = reinterpret_cast<const i32x4*>(vN + (size_t)(h * CD + dd) * CN + m0 + g * 8);
            st16(Vt, swzB(dd, g), *src);
        }
        __syncthreads();

        // ---- energy: wave w owns n rows [w*16, w*16+16), all 64 m cols
        f32x4 e[4];
        for (int s = 0; s < 4; ++s) e[s] = fz;
        #pragma unroll
        for (int kk = 0; kk < 4; ++kk) {
            bf16x8 af = ldfrag(Qt, swzA(w * 16 + (l & 15), kk * 4 + (l >> 4)));
            #pragma unroll
            for (int s = 0; s < 4; ++s) {
                bf16x8 bf = ldfrag(Kt, swzA(s * 16 + (l & 15), kk * 4 + (l >> 4)));
                e[s] = __builtin_amdgcn_mfma_f32_16x16x32_bf16(af, bf, e[s], 0, 0, 0);
            }
        }

        // ---- online softmax over m (rows n = w*16 + (l>>4)*4 + r)
        float sc[4];
        #pragma unroll
        for (int r = 0; r < 4; ++r) {
            float mx = fmaxf(fmaxf(e[0][r], e[1][r]), fmaxf(e[2][r], e[3][r]));
            #pragma unroll
            for (int msk = 1; msk < 16; msk <<= 1)
                mx = fmaxf(mx, __shfl_xor(mx, msk, 64));
            float mnew = fmaxf(mrun[r], mx);
            sc[r] = __expf(mrun[r] - mnew);
            float ts = 0.f;
            #pragma unroll
            for (int s = 0; s < 4; ++s) {
                float pv = __expf(e[s][r] - mnew);
                e[s][r] = pv;
                ts += pv;
            }
            #pragma unroll
            for (int msk = 1; msk < 16; msk <<= 1)
                ts += __shfl_xor(ts, msk, 64);
            lrun[r] = lrun[r] * sc[r] + ts;
            mrun[r] = mnew;
        }
        // write P (bf16) + per-row rescale factor
        #pragma unroll
        for (int r = 0; r < 4; ++r) {
            int nrow = w * 16 + (l >> 4) * 4 + r;
            #pragma unroll
            for (int s = 0; s < 4; ++s)
                st2(Pt, swzB_s(nrow, s * 16 + (l & 15)), f2bf(e[s][r]));
            if ((l & 15) == 0) scale_s[nrow] = sc[r];
        }
        __syncthreads();

        // ---- PV: wave w owns d rows [w*16, w*16+16); O[d][n] += V[d][m] P[n][m]
        #pragma unroll
        for (int s = 0; s < 4; ++s) {
            float scn = scale_s[s * 16 + (l & 15)];
            #pragma unroll
            for (int r = 0; r < 4; ++r) oacc[s][r] *= scn;
        }
        #pragma unroll
        for (int kk = 0; kk < 2; ++kk) {
            bf16x8 vf = ldfrag(Vt, swzB(w * 16 + (l & 15), kk * 4 + (l >> 4)));
            #pragma unroll
            for (int s = 0; s < 4; ++s) {
                bf16x8 pf = ldfrag(Pt, swzB(s * 16 + (l & 15), kk * 4 + (l >> 4)));
                oacc[s] = __builtin_amdgcn_mfma_f32_16x16x32_bf16(vf, pf, oacc[s], 0, 0, 0);
            }
        }
    }

    // ---- epilogue: publish row sums, normalize, store f32
    #pragma unroll
    for (int r = 0; r < 4; ++r) {
        int nrow = w * 16 + (l >> 4) * 4 + r;
        if ((l & 15) == 0) l_s[nrow] = lrun[r];
    }
    __syncthreads();
    float* outp = out + ((size_t)(br * CB + b) * CC + h * CD) * CN + n0;
    #pragma unroll
    for (int s = 0; s < 4; ++s) {
        int ncol = s * 16 + (l & 15);
        float inv = 1.f / l_s[ncol];
        #pragma unroll
        for (int r = 0; r < 4; ++r) {
            int drow = w * 16 + (l >> 4) * 4 + r;
            outp[(size_t)drow * CN + ncol] = oacc[s][r] * inv;
        }
    }
}

extern "C" void kernel_launch(void* const* d_in, const int* in_sizes, int n_in,
                              void* d_out, int out_size, void* d_ws, size_t ws_size,
                              hipStream_t stream) {
    const float* q1 = (const float*)d_in[0];
    const float* q2 = (const float*)d_in[1];
    const float* q3 = (const float*)d_in[2];
    const float* Wq = (const float*)d_in[3];
    const float* bq = (const float*)d_in[4];
    const float* Wk = (const float*)d_in[5];
    const float* bk = (const float*)d_in[6];
    const float* Wv = (const float*)d_in[7];
    const float* bv = (const float*)d_in[8];
    const float* rh = (const float*)d_in[9];
    const float* rw = (const float*)d_in[10];

    u16* projN = (u16*)d_ws;                       // 3 * B*C*N bf16 = 12 MB
    u16* projT = projN + (size_t)3 * CB * CC * CN; // 12 MB more
    float* outp = (float*)d_out;

    dim3 gp(CN / 64, CC / 64, 12);
    mqf_proj_kernel<<<gp, 256, 0, stream>>>(q1, q2, q3, Wq, bq, Wk, bk, Wv, bv, projN, projT);
    dim3 ga(CN / 64, CB * CH, 3);
    mqf_attn_kernel<<<ga, 256, 0, stream>>>(projN, projT, rh, rw, outp);
}

// Round 2
// 141.883 us; speedup vs baseline: 1.8614x; 1.8614x over previous
//
#include <hip/hip_runtime.h>

typedef __attribute__((ext_vector_type(8))) __bf16 bf16x8;
typedef __attribute__((ext_vector_type(4))) float f32x4;
typedef __attribute__((ext_vector_type(4))) int i32x4;
typedef __attribute__((ext_vector_type(4))) unsigned short u16x4;
typedef __attribute__((ext_vector_type(8))) unsigned short u16x8;
typedef unsigned short u16;
typedef unsigned int u32;

#define DEVI __device__ __forceinline__

constexpr int CB = 4;      // batch
constexpr int CC = 512;    // channels
constexpr int CH = 8;      // heads
constexpr int CD = 64;     // head dim
constexpr int CN = 1024;   // tokens (32*32)

DEVI u16 f2bf(float f) {
    u32 u = __builtin_bit_cast(u32, f);
    u = (u + 0x7FFFu + ((u >> 16) & 1u)) >> 16;
    return (u16)u;
}

// swizzled byte offsets: XOR bits 4-6 with row low bits (keeps 16B alignment)
DEVI int swzA(int row, int col16) {   // 256B-stride rows ([64][128] bf16)
    return (row * 256 + col16 * 16) ^ ((row & 7) << 4);
}
DEVI int swzB(int row, int col16) {   // 128B-stride rows ([*][64] bf16)
    return (row * 128 + col16 * 16) ^ ((row & 7) << 4);
}
DEVI int swzA_s(int row, int col) {
    return (row * 256 + col * 2) ^ ((row & 7) << 4);
}
DEVI int swzB_s(int row, int col) {
    return (row * 128 + col * 2) ^ ((row & 7) << 4);
}

DEVI bf16x8 ldfrag(const u16* base, int byteoff) {
    const i32x4* p = reinterpret_cast<const i32x4*>(reinterpret_cast<const char*>(base) + byteoff);
    return __builtin_bit_cast(bf16x8, *p);
}
DEVI void st16(u16* base, int byteoff, i32x4 v) {
    *reinterpret_cast<i32x4*>(reinterpret_cast<char*>(base) + byteoff) = v;
}
DEVI void st2(u16* base, int byteoff, u16 v) {
    *reinterpret_cast<u16*>(reinterpret_cast<char*>(base) + byteoff) = v;
}
DEVI void async16(u16* lds, const u16* g) {
    __builtin_amdgcn_global_load_lds(
        (const __attribute__((address_space(1))) unsigned int*)g,
        (__attribute__((address_space(3))) unsigned int*)lds,
        16, 0, 0);
}

// ---------------------------------------------------------------------------
// convX: q{1,2,3} f32 [b][c][n]  ->  XT bf16 [p][b][n][c]  (transposed)
// ---------------------------------------------------------------------------
__global__ __launch_bounds__(256) void mqf_convx_kernel(
    const float* __restrict__ q1, const float* __restrict__ q2, const float* __restrict__ q3,
    u16* __restrict__ XT)
{
    __shared__ u16 T[64 * 66];   // [c_local][n_local] stride 66
    const int t = threadIdx.x;
    const int n0 = blockIdx.x * 64, c0 = blockIdx.y * 64;
    const int p = blockIdx.z >> 2, b = blockIdx.z & 3;
    const float* X = (p == 0 ? q1 : p == 1 ? q2 : q3) + (size_t)b * CC * CN;
    u16* dst = XT + (size_t)(p * CB + b) * CN * CC;

    #pragma unroll
    for (int pass = 0; pass < 4; ++pass) {
        int idx = pass * 256 + t;
        int cl = idx >> 4, nl = (idx & 15) * 4;
        f32x4 v = *reinterpret_cast<const f32x4*>(X + (size_t)(c0 + cl) * CN + n0 + nl);
        u32 lo = (u32)f2bf(v[0]) | ((u32)f2bf(v[1]) << 16);
        u32 hi = (u32)f2bf(v[2]) | ((u32)f2bf(v[3]) << 16);
        *reinterpret_cast<u32*>(&T[cl * 66 + nl]) = lo;
        *reinterpret_cast<u32*>(&T[cl * 66 + nl + 2]) = hi;
    }
    __syncthreads();
    #pragma unroll
    for (int pass = 0; pass < 2; ++pass) {
        int idx = pass * 256 + t;
        int nl = idx >> 3, g = idx & 7;
        u16x8 pk;
        #pragma unroll
        for (int j = 0; j < 8; ++j) pk[j] = T[(g * 8 + j) * 66 + nl];
        *reinterpret_cast<u16x8*>(dst + (size_t)(n0 + nl) * CC + c0 + g * 8) = pk;
    }
}

// ---------------------------------------------------------------------------
// convW: Wq/Wk/Wv f32 [o][c] -> Wbf bf16 [p][o][c]
// ---------------------------------------------------------------------------
__global__ __launch_bounds__(256) void mqf_convw_kernel(
    const float* __restrict__ Wq, const float* __restrict__ Wk, const float* __restrict__ Wv,
    u16* __restrict__ Wbf)
{
    int idx = (blockIdx.x * 256 + threadIdx.x) * 4;
    int p = idx >> 18;                 // 512*512 = 2^18
    int off = idx & 0x3FFFF;
    const float* W = (p == 0 ? Wq : p == 1 ? Wk : Wv);
    f32x4 v = *reinterpret_cast<const f32x4*>(W + off);
    u16x4 pk;
    #pragma unroll
    for (int j = 0; j < 4; ++j) pk[j] = f2bf(v[j]);
    *reinterpret_cast<u16x4*>(Wbf + idx) = pk;
}

// ---------------------------------------------------------------------------
// Projection GEMM: Y[o,n] = sum_c Wbf[p][o,c] XT[p][b][n,c] + b[o]
// 128x128 tile, BK=64, global_load_lds(16B) with pre-swizzled source.
// Writes bf16 in [o][n] (projN) and [n][o] (projT).
// ---------------------------------------------------------------------------
__global__ __launch_bounds__(256) void mqf_gemm_kernel(
    const u16* __restrict__ Wbf, const u16* __restrict__ XT,
    const float* __restrict__ bq, const float* __restrict__ bk, const float* __restrict__ bv,
    u16* __restrict__ projN, u16* __restrict__ projT)
{
    __shared__ __align__(16) u16 At[128 * 64];
    __shared__ __align__(16) u16 Bt[128 * 64];

    const int t = threadIdx.x;
    const int w = t >> 6, l = t & 63;
    const int n0 = blockIdx.x * 128;
    const int o0 = blockIdx.y * 128;
    const int p = blockIdx.z >> 2, b = blockIdx.z & 3;

    const u16* A = Wbf + (size_t)p * CC * CC;                 // [o][c]
    const u16* B = XT + (size_t)(p * CB + b) * CN * CC;       // [n][c]
    const float* bm = (p == 0 ? bq : p == 1 ? bk : bv);
    u16* oN = projN + (size_t)(p * CB + b) * CC * CN;
    u16* oT = projT + (size_t)(p * CB + b) * CN * CC;

    const int srow = t >> 3;      // 0..31 within 32-row chunk
    const int sj = t & 7;         // 16B unit within 128B row

    const f32x4 fz = {0.f, 0.f, 0.f, 0.f};
    f32x4 acc[4][4];
    #pragma unroll
    for (int m = 0; m < 4; ++m)
        #pragma unroll
        for (int s = 0; s < 4; ++s) acc[m][s] = fz;

    const int wr = (w >> 1) * 64;   // wave M offset in tile
    const int wc = (w & 1) * 64;    // wave N offset in tile

    for (int c0 = 0; c0 < CC; c0 += 64) {
        __syncthreads();
        #pragma unroll
        for (int q = 0; q < 4; ++q) {
            int row = q * 32 + srow;
            int col = (sj ^ (row & 7)) * 8;   // pre-swizzled source column
            async16(&At[q * 2048 + t * 8], A + (size_t)(o0 + row) * CC + c0 + col);
            async16(&Bt[q * 2048 + t * 8], B + (size_t)(n0 + row) * CC + c0 + col);
        }
        __syncthreads();
        __builtin_amdgcn_s_setprio(1);
        #pragma unroll
        for (int kk = 0; kk < 2; ++kk) {
            bf16x8 af[4], bfr[4];
            #pragma unroll
            for (int m = 0; m < 4; ++m)
                af[m] = ldfrag(At, swzB(wr + m * 16 + (l & 15), kk * 4 + (l >> 4)));
            #pragma unroll
            for (int s = 0; s < 4; ++s)
                bfr[s] = ldfrag(Bt, swzB(wc + s * 16 + (l & 15), kk * 4 + (l >> 4)));
            #pragma unroll
            for (int m = 0; m < 4; ++m)
                #pragma unroll
                for (int s = 0; s < 4; ++s)
                    acc[m][s] = __builtin_amdgcn_mfma_f32_16x16x32_bf16(af[m], bfr[s], acc[m][s], 0, 0, 0);
        }
        __builtin_amdgcn_s_setprio(0);
    }

    // epilogue: bias + dual-layout bf16 store
    #pragma unroll
    for (int m = 0; m < 4; ++m) {
        int obase = o0 + wr + m * 16 + (l >> 4) * 4;
        float bias[4];
        #pragma unroll
        for (int r = 0; r < 4; ++r) bias[r] = bm[obase + r];
        #pragma unroll
        for (int s = 0; s < 4; ++s) {
            int n = n0 + wc + s * 16 + (l & 15);
            u16x4 pk;
            #pragma unroll
            for (int r = 0; r < 4; ++r) {
                float v = acc[m][s][r] + bias[r];
                pk[r] = f2bf(v);
                oN[(size_t)(obase + r) * CN + n] = pk[r];
            }
            *reinterpret_cast<u16x4*>(oT + (size_t)n * CC + obase) = pk;
        }
    }
}

// ---------------------------------------------------------------------------
// Attention: one block = 64 query rows of one (branch, b, h).
// Q'=[a;pos] (128), K'=[bm;a] (128), V=outv (64). Flash-style online softmax.
// ---------------------------------------------------------------------------
__global__ __launch_bounds__(256) void mqf_attn_kernel(
    const u16* __restrict__ projN, const u16* __restrict__ projT,
    const float* __restrict__ rel_h, const float* __restrict__ rel_w,
    float* __restrict__ out)
{
    __shared__ __align__(16) u16 Qt[64 * 128];  // [n][dd] swizzled
    __shared__ __align__(16) u16 Kt[64 * 128];  // [m][dd] swizzled
    __shared__ __align__(16) u16 Vt[64 * 64];   // [d][m]  swizzled
    __shared__ __align__(16) u16 Pt[64 * 64];   // [n][m]  swizzled
    __shared__ float scale_s[64];
    __shared__ float l_s[64];

    const int t = threadIdx.x;
    const int w = t >> 6, l = t & 63;
    const int n0 = blockIdx.x * 64;
    const int b = blockIdx.y >> 3, h = blockIdx.y & 7;
    const int br = blockIdx.z;

    const int ai = br, bi = (br + 1) % 3, vi = (br + 2) % 3;
    const size_t tsz = (size_t)CB * CC * CN;
    const u16* aT = projT + ai * tsz + (size_t)b * CN * CC;  // [n][o]
    const u16* bT = projT + bi * tsz + (size_t)b * CN * CC;  // [n][o]
    const u16* vN = projN + vi * tsz + (size_t)b * CC * CN;  // [o][n]

    // ---- stage Qt: rows n0..n0+63, dd 0..127 (a | pos)
    #pragma unroll
    for (int pass = 0; pass < 2; ++pass) {
        int idx = pass * 256 + t;
        int nn = idx >> 3, g = idx & 7;
        const i32x4* src = reinterpret_cast<const i32x4*>(aT + (size_t)(n0 + nn) * CC + h * CD + g * 8);
        st16(Qt, swzA(nn, g), *src);
    }
    #pragma unroll
    for (int pass = 0; pass < 16; ++pass) {
        int nn = t & 63;
        int d = (t >> 6) + pass * 4;
        int ng = n0 + nn;
        float f = rel_h[(h * CD + d) * 32 + (ng & 31)] + rel_w[(h * CD + d) * 32 + (ng >> 5)];
        st2(Qt, swzA_s(nn, 64 + d), f2bf(f));
    }

    const f32x4 fz = {0.f, 0.f, 0.f, 0.f};
    f32x4 oacc[4];
    for (int s = 0; s < 4; ++s) oacc[s] = fz;
    float mrun[4], lrun[4];
    for (int r = 0; r < 4; ++r) { mrun[r] = -1e30f; lrun[r] = 0.f; }

    for (int m0 = 0; m0 < CN; m0 += 64) {
        __syncthreads();  // previous tile's LDS reads done
        // ---- stage Kt: [m][0:64]=bm, [m][64:128]=a
        #pragma unroll
        for (int pass = 0; pass < 4; ++pass) {
            int idx = pass * 256 + t;
            int mm = idx >> 4, g = idx & 15;
            const u16* sp = (g < 8)
                ? (bT + (size_t)(m0 + mm) * CC + h * CD + g * 8)
                : (aT + (size_t)(m0 + mm) * CC + h * CD + (g - 8) * 8);
            st16(Kt, swzA(mm, g), *reinterpret_cast<const i32x4*>(sp));
        }
        // ---- stage Vt: [d][m]
        #pragma unroll
        for (int pass = 0; pass < 2; ++pass) {
            int idx = pass * 256 + t;
            int dd = idx >> 3, g = idx & 7;
            const i32x4* src = reinterpret_cast<const i32x4*>(vN + (size_t)(h * CD + dd) * CN + m0 + g * 8);
            st16(Vt, swzB(dd, g), *src);
        }
        __syncthreads();

        // ---- energy: wave w owns n rows [w*16, w*16+16), all 64 m cols
        f32x4 e[4];
        for (int s = 0; s < 4; ++s) e[s] = fz;
        __builtin_amdgcn_s_setprio(1);
        #pragma unroll
        for (int kk = 0; kk < 4; ++kk) {
            bf16x8 af = ldfrag(Qt, swzA(w * 16 + (l & 15), kk * 4 + (l >> 4)));
            #pragma unroll
            for (int s = 0; s < 4; ++s) {
                bf16x8 bf = ldfrag(Kt, swzA(s * 16 + (l & 15), kk * 4 + (l >> 4)));
                e[s] = __builtin_amdgcn_mfma_f32_16x16x32_bf16(af, bf, e[s], 0, 0, 0);
            }
        }
        __builtin_amdgcn_s_setprio(0);

        // ---- online softmax over m (rows n = w*16 + (l>>4)*4 + r)
        float sc[4];
        #pragma unroll
        for (int r = 0; r < 4; ++r) {
            float mx = fmaxf(fmaxf(e[0][r], e[1][r]), fmaxf(e[2][r], e[3][r]));
            #pragma unroll
            for (int msk = 1; msk < 16; msk <<= 1)
                mx = fmaxf(mx, __shfl_xor(mx, msk, 64));
            float mnew = fmaxf(mrun[r], mx);
            sc[r] = __expf(mrun[r] - mnew);
            float ts = 0.f;
            #pragma unroll
            for (int s = 0; s < 4; ++s) {
                float pv = __expf(e[s][r] - mnew);
                e[s][r] = pv;
                ts += pv;
            }
            #pragma unroll
            for (int msk = 1; msk < 16; msk <<= 1)
                ts += __shfl_xor(ts, msk, 64);
            lrun[r] = lrun[r] * sc[r] + ts;
            mrun[r] = mnew;
        }
        // write P (bf16) + per-row rescale factor
        #pragma unroll
        for (int r = 0; r < 4; ++r) {
            int nrow = w * 16 + (l >> 4) * 4 + r;
            #pragma unroll
            for (int s = 0; s < 4; ++s)
                st2(Pt, swzB_s(nrow, s * 16 + (l & 15)), f2bf(e[s][r]));
            if ((l & 15) == 0) scale_s[nrow] = sc[r];
        }
        __syncthreads();

        // ---- PV: wave w owns d rows [w*16, w*16+16); O[d][n] += V[d][m] P[n][m]
        #pragma unroll
        for (int s = 0; s < 4; ++s) {
            float scn = scale_s[s * 16 + (l & 15)];
            #pragma unroll
            for (int r = 0; r < 4; ++r) oacc[s][r] *= scn;
        }
        __builtin_amdgcn_s_setprio(1);
        #pragma unroll
        for (int kk = 0; kk < 2; ++kk) {
            bf16x8 vf = ldfrag(Vt, swzB(w * 16 + (l & 15), kk * 4 + (l >> 4)));
            #pragma unroll
            for (int s = 0; s < 4; ++s) {
                bf16x8 pf = ldfrag(Pt, swzB(s * 16 + (l & 15), kk * 4 + (l >> 4)));
                oacc[s] = __builtin_amdgcn_mfma_f32_16x16x32_bf16(vf, pf, oacc[s], 0, 0, 0);
            }
        }
        __builtin_amdgcn_s_setprio(0);
    }

    // ---- epilogue: publish row sums, normalize, store f32
    #pragma unroll
    for (int r = 0; r < 4; ++r) {
        int nrow = w * 16 + (l >> 4) * 4 + r;
        if ((l & 15) == 0) l_s[nrow] = lrun[r];
    }
    __syncthreads();
    float* outp = out + ((size_t)(br * CB + b) * CC + h * CD) * CN + n0;
    #pragma unroll
    for (int s = 0; s < 4; ++s) {
        int ncol = s * 16 + (l & 15);
        float inv = 1.f / l_s[ncol];
        #pragma unroll
        for (int r = 0; r < 4; ++r) {
            int drow = w * 16 + (l >> 4) * 4 + r;
            outp[(size_t)drow * CN + ncol] = oacc[s][r] * inv;
        }
    }
}

extern "C" void kernel_launch(void* const* d_in, const int* in_sizes, int n_in,
                              void* d_out, int out_size, void* d_ws, size_t ws_size,
                              hipStream_t stream) {
    const float* q1 = (const float*)d_in[0];
    const float* q2 = (const float*)d_in[1];
    const float* q3 = (const float*)d_in[2];
    const float* Wq = (const float*)d_in[3];
    const float* bq = (const float*)d_in[4];
    const float* Wk = (const float*)d_in[5];
    const float* bk = (const float*)d_in[6];
    const float* Wv = (const float*)d_in[7];
    const float* bv = (const float*)d_in[8];
    const float* rh = (const float*)d_in[9];
    const float* rw = (const float*)d_in[10];

    u16* XT    = (u16*)d_ws;                          // 3*B*N*C bf16 = 12.6 MB
    u16* Wbf   = XT + (size_t)3 * CB * CN * CC;       // 1.5 MB
    u16* projN = Wbf + (size_t)3 * CC * CC;           // 12.6 MB
    u16* projT = projN + (size_t)3 * CB * CC * CN;    // 12.6 MB
    float* outp = (float*)d_out;

    dim3 gc(CN / 64, CC / 64, 12);
    mqf_convx_kernel<<<gc, 256, 0, stream>>>(q1, q2, q3, XT);
    mqf_convw_kernel<<<768, 256, 0, stream>>>(Wq, Wk, Wv, Wbf);
    dim3 gg(CN / 128, CC / 128, 12);
    mqf_gemm_kernel<<<gg, 256, 0, stream>>>(Wbf, XT, bq, bk, bv, projN, projT);
    dim3 ga(CN / 64, CB * CH, 3);
    mqf_attn_kernel<<<ga, 256, 0, stream>>>(projN, projT, rh, rw, outp);
}

// Round 3
// 103.533 us; speedup vs baseline: 2.5509x; 1.3704x over previous
//
#include <hip/hip_runtime.h>

typedef __attribute__((ext_vector_type(8))) __bf16 bf16x8;
typedef __attribute__((ext_vector_type(4))) float f32x4;
typedef __attribute__((ext_vector_type(4))) int i32x4;
typedef __attribute__((ext_vector_type(4))) unsigned short u16x4;
typedef __attribute__((ext_vector_type(8))) unsigned short u16x8;
typedef unsigned short u16;
typedef unsigned int u32;

#define DEVI __device__ __forceinline__

constexpr int CB = 4;      // batch
constexpr int CC = 512;    // channels
constexpr int CH = 8;      // heads
constexpr int CD = 64;     // head dim
constexpr int CN = 1024;   // tokens (32*32)

DEVI u16 f2bf(float f) {
    u32 u = __builtin_bit_cast(u32, f);
    u = (u + 0x7FFFu + ((u >> 16) & 1u)) >> 16;
    return (u16)u;
}

// swizzled byte offsets: XOR bits 4-6 with row low bits (16B-unit swizzle)
DEVI int swzA(int row, int col16) {   // 256B-stride rows ([64][128] bf16)
    return (row * 256 + col16 * 16) ^ ((row & 7) << 4);
}
DEVI int swzB(int row, int col16) {   // 128B-stride rows ([*][64] bf16)
    return (row * 128 + col16 * 16) ^ ((row & 7) << 4);
}

DEVI bf16x8 ldfrag(const u16* base, int byteoff) {
    const i32x4* p = reinterpret_cast<const i32x4*>(reinterpret_cast<const char*>(base) + byteoff);
    return __builtin_bit_cast(bf16x8, *p);
}
DEVI void st16(u16* base, int byteoff, i32x4 v) {
    *reinterpret_cast<i32x4*>(reinterpret_cast<char*>(base) + byteoff) = v;
}
DEVI void st8(u16* base, int byteoff, u16x4 v) {
    *reinterpret_cast<u16x4*>(reinterpret_cast<char*>(base) + byteoff) = v;
}
DEVI void async16(u16* lds, const u16* g) {
    __builtin_amdgcn_global_load_lds(
        (const __attribute__((address_space(1))) unsigned int*)g,
        (__attribute__((address_space(3))) unsigned int*)lds,
        16, 0, 0);
}

// ---------------------------------------------------------------------------
// convX: q{1,2,3} f32 [b][c][n]  ->  XT bf16 [p][b][n][c]  (transposed)
// ---------------------------------------------------------------------------
__global__ __launch_bounds__(256) void mqf_convx_kernel(
    const float* __restrict__ q1, const float* __restrict__ q2, const float* __restrict__ q3,
    u16* __restrict__ XT)
{
    __shared__ u16 T[64 * 66];   // [c_local][n_local] stride 66
    const int t = threadIdx.x;
    const int n0 = blockIdx.x * 64, c0 = blockIdx.y * 64;
    const int p = blockIdx.z >> 2, b = blockIdx.z & 3;
    const float* X = (p == 0 ? q1 : p == 1 ? q2 : q3) + (size_t)b * CC * CN;
    u16* dst = XT + (size_t)(p * CB + b) * CN * CC;

    #pragma unroll
    for (int pass = 0; pass < 4; ++pass) {
        int idx = pass * 256 + t;
        int cl = idx >> 4, nl = (idx & 15) * 4;
        f32x4 v = *reinterpret_cast<const f32x4*>(X + (size_t)(c0 + cl) * CN + n0 + nl);
        u32 lo = (u32)f2bf(v[0]) | ((u32)f2bf(v[1]) << 16);
        u32 hi = (u32)f2bf(v[2]) | ((u32)f2bf(v[3]) << 16);
        *reinterpret_cast<u32*>(&T[cl * 66 + nl]) = lo;
        *reinterpret_cast<u32*>(&T[cl * 66 + nl + 2]) = hi;
    }
    __syncthreads();
    #pragma unroll
    for (int pass = 0; pass < 2; ++pass) {
        int idx = pass * 256 + t;
        int nl = idx >> 3, g = idx & 7;
        u16x8 pk;
        #pragma unroll
        for (int j = 0; j < 8; ++j) pk[j] = T[(g * 8 + j) * 66 + nl];
        *reinterpret_cast<u16x8*>(dst + (size_t)(n0 + nl) * CC + c0 + g * 8) = pk;
    }
}

// ---------------------------------------------------------------------------
// convW: Wq/Wk/Wv f32 [o][c] -> Wbf bf16 [p][o][c]
// ---------------------------------------------------------------------------
__global__ __launch_bounds__(256) void mqf_convw_kernel(
    const float* __restrict__ Wq, const float* __restrict__ Wk, const float* __restrict__ Wv,
    u16* __restrict__ Wbf)
{
    int idx = (blockIdx.x * 256 + threadIdx.x) * 4;
    int p = idx >> 18;                 // 512*512 = 2^18
    int off = idx & 0x3FFFF;
    const float* W = (p == 0 ? Wq : p == 1 ? Wk : Wv);
    f32x4 v = *reinterpret_cast<const f32x4*>(W + off);
    u16x4 pk;
    #pragma unroll
    for (int j = 0; j < 4; ++j) pk[j] = f2bf(v[j]);
    *reinterpret_cast<u16x4*>(Wbf + idx) = pk;
}

// ---------------------------------------------------------------------------
// Projection GEMM: Y[o,n] = sum_c Wbf[p][o,c] XT[p][b][n,c] + b[o]
// 128x128 tile, BK=64, global_load_lds(16B) with pre-swizzled source.
// ---------------------------------------------------------------------------
__global__ __launch_bounds__(256) void mqf_gemm_kernel(
    const u16* __restrict__ Wbf, const u16* __restrict__ XT,
    const float* __restrict__ bq, const float* __restrict__ bk, const float* __restrict__ bv,
    u16* __restrict__ projN, u16* __restrict__ projT)
{
    __shared__ __align__(16) u16 At[128 * 64];
    __shared__ __align__(16) u16 Bt[128 * 64];

    const int t = threadIdx.x;
    const int w = t >> 6, l = t & 63;
    const int n0 = blockIdx.x * 128;
    const int o0 = blockIdx.y * 128;
    const int p = blockIdx.z >> 2, b = blockIdx.z & 3;

    const u16* A = Wbf + (size_t)p * CC * CC;                 // [o][c]
    const u16* B = XT + (size_t)(p * CB + b) * CN * CC;       // [n][c]
    const float* bm = (p == 0 ? bq : p == 1 ? bk : bv);
    u16* oN = projN + (size_t)(p * CB + b) * CC * CN;
    u16* oT = projT + (size_t)(p * CB + b) * CN * CC;

    const int srow = t >> 3;      // 0..31 within 32-row chunk
    const int sj = t & 7;         // 16B unit within 128B row

    const f32x4 fz = {0.f, 0.f, 0.f, 0.f};
    f32x4 acc[4][4];
    #pragma unroll
    for (int m = 0; m < 4; ++m)
        #pragma unroll
        for (int s = 0; s < 4; ++s) acc[m][s] = fz;

    const int wr = (w >> 1) * 64;   // wave M offset in tile
    const int wc = (w & 1) * 64;    // wave N offset in tile

    for (int c0 = 0; c0 < CC; c0 += 64) {
        __syncthreads();
        #pragma unroll
        for (int q = 0; q < 4; ++q) {
            int row = q * 32 + srow;
            int col = (sj ^ (row & 7)) * 8;   // pre-swizzled source column
            async16(&At[q * 2048 + t * 8], A + (size_t)(o0 + row) * CC + c0 + col);
            async16(&Bt[q * 2048 + t * 8], B + (size_t)(n0 + row) * CC + c0 + col);
        }
        __syncthreads();
        __builtin_amdgcn_s_setprio(1);
        #pragma unroll
        for (int kk = 0; kk < 2; ++kk) {
            bf16x8 af[4], bfr[4];
            #pragma unroll
            for (int m = 0; m < 4; ++m)
                af[m] = ldfrag(At, swzB(wr + m * 16 + (l & 15), kk * 4 + (l >> 4)));
            #pragma unroll
            for (int s = 0; s < 4; ++s)
                bfr[s] = ldfrag(Bt, swzB(wc + s * 16 + (l & 15), kk * 4 + (l >> 4)));
            #pragma unroll
            for (int m = 0; m < 4; ++m)
                #pragma unroll
                for (int s = 0; s < 4; ++s)
                    acc[m][s] = __builtin_amdgcn_mfma_f32_16x16x32_bf16(af[m], bfr[s], acc[m][s], 0, 0, 0);
        }
        __builtin_amdgcn_s_setprio(0);
    }

    #pragma unroll
    for (int m = 0; m < 4; ++m) {
        int obase = o0 + wr + m * 16 + (l >> 4) * 4;
        float bias[4];
        #pragma unroll
        for (int r = 0; r < 4; ++r) bias[r] = bm[obase + r];
        #pragma unroll
        for (int s = 0; s < 4; ++s) {
            int n = n0 + wc + s * 16 + (l & 15);
            u16x4 pk;
            #pragma unroll
            for (int r = 0; r < 4; ++r) {
                float v = acc[m][s][r] + bias[r];
                pk[r] = f2bf(v);
                oN[(size_t)(obase + r) * CN + n] = pk[r];
            }
            *reinterpret_cast<u16x4*>(oT + (size_t)n * CC + obase) = pk;
        }
    }
}

// ---------------------------------------------------------------------------
// Attention (swapped-QK layout): one block = 64 query rows of one (br, b, h).
// e = mfma(K',Q') so each lane owns column n = w*16+(l&15), m-values in regs.
// Q' in registers; K/V reg-staged async into swizzled LDS; P packed 8B.
// ---------------------------------------------------------------------------
__global__ __launch_bounds__(256, 4) void mqf_attn_kernel(
    const u16* __restrict__ projN, const u16* __restrict__ projT,
    const float* __restrict__ rel_h, const float* __restrict__ rel_w,
    float* __restrict__ out)
{
    __shared__ __align__(16) u16 Kt[64 * 128];  // [m][dd] swizzled (16KB)
    __shared__ __align__(16) u16 Vt[64 * 64];   // [d][m]  swizzled (8KB)
    __shared__ __align__(16) u16 Pt[64 * 64];   // [n][m]  swizzled (8KB)
    __shared__ float scale_s[64];
    __shared__ float l_s[64];

    const int t = threadIdx.x;
    const int w = t >> 6, l = t & 63;
    const int li = l & 15, hi = l >> 4;

    // bijective XCD swizzle: 1536 blocks, 8 XCDs, 192/XCD; blocks sharing a
    // (b,h,br) K/V panel (16 n0 tiles) land on the same XCD.
    int id = blockIdx.x + (blockIdx.y << 4) + (blockIdx.z << 9);
    int nid = (id & 7) * 192 + (id >> 3);
    const int n0 = (nid & 15) * 64;
    const int by = (nid >> 4) & 31;
    const int br = nid >> 9;
    const int b = by >> 3, h = by & 7;

    const int ai = br, bi = (br + 1) % 3, vi = (br + 2) % 3;
    const size_t tsz = (size_t)CB * CC * CN;
    const u16* aT = projT + ai * tsz + (size_t)b * CN * CC;  // [n][o]
    const u16* bT = projT + bi * tsz + (size_t)b * CN * CC;  // [n][o]
    const u16* vN = projN + vi * tsz + (size_t)b * CC * CN;  // [o][n]

    // ---- Q' fragments in registers (B-operand): row n = n0 + w*16 + li,
    // k-window kk*32 + hi*8 + j.  kk=0,1: a; kk=2,3: pos.
    const int nq = n0 + w * 16 + li;
    bf16x8 qf[4];
    #pragma unroll
    for (int kk = 0; kk < 2; ++kk)
        qf[kk] = __builtin_bit_cast(bf16x8, *reinterpret_cast<const i32x4*>(
            aT + (size_t)nq * CC + h * CD + kk * 32 + hi * 8));
    #pragma unroll
    for (int kk = 2; kk < 4; ++kk) {
        u16x8 pk;
        #pragma unroll
        for (int j = 0; j < 8; ++j) {
            int d = (kk - 2) * 32 + hi * 8 + j;
            float f = rel_h[(h * CD + d) * 32 + (nq & 31)]
                    + rel_w[(h * CD + d) * 32 + (nq >> 5)];
            pk[j] = f2bf(f);
        }
        qf[kk] = __builtin_bit_cast(bf16x8, pk);
    }

    const f32x4 fz = {0.f, 0.f, 0.f, 0.f};
    f32x4 oacc[4];
    #pragma unroll
    for (int s = 0; s < 4; ++s) oacc[s] = fz;
    float mrun = -1e30f, lrun = 0.f;

    // ---- async K/V staging registers (T14): global -> reg now, LDS later
    i32x4 kreg[4], vreg[2];
    const int krow = t >> 2, kc = (t & 3) * 8;
    const int vrow = t >> 3, vc = (t & 7) * 8;
    {
        const u16* rb = bT + (size_t)krow * CC + h * CD;
        const u16* ra = aT + (size_t)krow * CC + h * CD;
        kreg[0] = *reinterpret_cast<const i32x4*>(rb + kc);
        kreg[1] = *reinterpret_cast<const i32x4*>(rb + 32 + kc);
        kreg[2] = *reinterpret_cast<const i32x4*>(ra + kc);
        kreg[3] = *reinterpret_cast<const i32x4*>(ra + 32 + kc);
        const u16* rv = vN + (size_t)(h * CD + vrow) * CN;
        vreg[0] = *reinterpret_cast<const i32x4*>(rv + vc);
        vreg[1] = *reinterpret_cast<const i32x4*>(rv + (size_t)32 * CN + vc);
    }

    for (int m0 = 0; m0 < CN; m0 += 64) {
        __syncthreads();   // all reads of previous Kt/Vt/Pt complete
        // publish staged regs to swizzled LDS
        {
            const int k7 = krow & 7;
            #pragma unroll
            for (int q = 0; q < 4; ++q) {
                int u = q * 4 + (t & 3);
                st16(Kt, krow * 256 + ((u ^ k7) << 4), kreg[q]);
            }
            st16(Vt, vrow * 128 + ((((t & 7)) ^ (vrow & 7)) << 4), vreg[0]);
            int vrow1 = vrow + 32;
            st16(Vt, vrow1 * 128 + ((((t & 7)) ^ (vrow1 & 7)) << 4), vreg[1]);
        }
        __syncthreads();
        // issue next tile's global loads (land during QK+softmax+PV)
        if (m0 + 64 < CN) {
            const int m1 = m0 + 64;
            const u16* rb = bT + (size_t)(m1 + krow) * CC + h * CD;
            const u16* ra = aT + (size_t)(m1 + krow) * CC + h * CD;
            kreg[0] = *reinterpret_cast<const i32x4*>(rb + kc);
            kreg[1] = *reinterpret_cast<const i32x4*>(rb + 32 + kc);
            kreg[2] = *reinterpret_cast<const i32x4*>(ra + kc);
            kreg[3] = *reinterpret_cast<const i32x4*>(ra + 32 + kc);
            const u16* rv = vN + (size_t)(h * CD + vrow) * CN + m1;
            vreg[0] = *reinterpret_cast<const i32x4*>(rv + vc);
            vreg[1] = *reinterpret_cast<const i32x4*>(rv + (size_t)32 * CN + vc);
        }

        // ---- QK^T (swapped): e[s][r] = energy[m = s*16+hi*4+r][n = w*16+li]
        f32x4 e[4];
        #pragma unroll
        for (int s = 0; s < 4; ++s) e[s] = fz;
        __builtin_amdgcn_s_setprio(1);
        #pragma unroll
        for (int kk = 0; kk < 4; ++kk) {
            #pragma unroll
            for (int s = 0; s < 4; ++s) {
                bf16x8 af = ldfrag(Kt, swzA(s * 16 + li, kk * 4 + hi));
                e[s] = __builtin_amdgcn_mfma_f32_16x16x32_bf16(af, qf[kk], e[s], 0, 0, 0);
            }
        }
        __builtin_amdgcn_s_setprio(0);

        // ---- online softmax for column n: register tree + 2 shuffles
        float mx = fmaxf(fmaxf(e[0][0], e[0][1]), fmaxf(e[0][2], e[0][3]));
        #pragma unroll
        for (int s = 1; s < 4; ++s)
            mx = fmaxf(mx, fmaxf(fmaxf(e[s][0], e[s][1]), fmaxf(e[s][2], e[s][3])));
        mx = fmaxf(mx, __shfl_xor(mx, 16, 64));
        mx = fmaxf(mx, __shfl_xor(mx, 32, 64));
        float mnew = fmaxf(mrun, mx);
        float sc = __expf(mrun - mnew);
        float ts = 0.f;
        #pragma unroll
        for (int s = 0; s < 4; ++s) {
            #pragma unroll
            for (int r = 0; r < 4; ++r) {
                float pv = __expf(e[s][r] - mnew);
                e[s][r] = pv;
                ts += pv;
            }
        }
        ts += __shfl_xor(ts, 16, 64);
        ts += __shfl_xor(ts, 32, 64);
        lrun = lrun * sc + ts;
        mrun = mnew;

        // ---- P -> LDS, packed 8B per (s); row n = w*16+li, cols s*16+hi*4
        {
            int prow = w * 16 + li;
            int pswz = (li & 7) << 4;
            #pragma unroll
            for (int s = 0; s < 4; ++s) {
                u16x4 pk;
                #pragma unroll
                for (int r = 0; r < 4; ++r) pk[r] = f2bf(e[s][r]);
                st8(Pt, (prow * 128 + s * 32 + hi * 8) ^ pswz, pk);
            }
            if (hi == 0) scale_s[prow] = sc;
        }
        __syncthreads();

        // ---- rescale + PV: oacc[s][r] = O[d = w*16+hi*4+r][n = s*16+li]
        #pragma unroll
        for (int s = 0; s < 4; ++s) {
            float scn = scale_s[s * 16 + li];
            #pragma unroll
            for (int r = 0; r < 4; ++r) oacc[s][r] *= scn;
        }
        __builtin_amdgcn_s_setprio(1);
        #pragma unroll
        for (int kk = 0; kk < 2; ++kk) {
            bf16x8 vf = ldfrag(Vt, swzB(w * 16 + li, kk * 4 + hi));
            #pragma unroll
            for (int s = 0; s < 4; ++s) {
                bf16x8 pf = ldfrag(Pt, swzB(s * 16 + li, kk * 4 + hi));
                oacc[s] = __builtin_amdgcn_mfma_f32_16x16x32_bf16(vf, pf, oacc[s], 0, 0, 0);
            }
        }
        __builtin_amdgcn_s_setprio(0);
    }

    // ---- epilogue
    if (hi == 0) l_s[w * 16 + li] = lrun;
    __syncthreads();
    float* outp = out + ((size_t)(br * CB + b) * CC + h * CD) * CN + n0;
    #pragma unroll
    for (int s = 0; s < 4; ++s) {
        float inv = 1.f / l_s[s * 16 + li];
        #pragma unroll
        for (int r = 0; r < 4; ++r) {
            int drow = w * 16 + hi * 4 + r;
            outp[(size_t)drow * CN + s * 16 + li] = oacc[s][r] * inv;
        }
    }
}

extern "C" void kernel_launch(void* const* d_in, const int* in_sizes, int n_in,
                              void* d_out, int out_size, void* d_ws, size_t ws_size,
                              hipStream_t stream) {
    const float* q1 = (const float*)d_in[0];
    const float* q2 = (const float*)d_in[1];
    const float* q3 = (const float*)d_in[2];
    const float* Wq = (const float*)d_in[3];
    const float* bq = (const float*)d_in[4];
    const float* Wk = (const float*)d_in[5];
    const float* bk = (const float*)d_in[6];
    const float* Wv = (const float*)d_in[7];
    const float* bv = (const float*)d_in[8];
    const float* rh = (const float*)d_in[9];
    const float* rw = (const float*)d_in[10];

    u16* XT    = (u16*)d_ws;                          // 12.6 MB
    u16* Wbf   = XT + (size_t)3 * CB * CN * CC;       // 1.5 MB
    u16* projN = Wbf + (size_t)3 * CC * CC;           // 12.6 MB
    u16* projT = projN + (size_t)3 * CB * CC * CN;    // 12.6 MB
    float* outp = (float*)d_out;

    dim3 gc(CN / 64, CC / 64, 12);
    mqf_convx_kernel<<<gc, 256, 0, stream>>>(q1, q2, q3, XT);
    mqf_convw_kernel<<<768, 256, 0, stream>>>(Wq, Wk, Wv, Wbf);
    dim3 gg(CN / 128, CC / 128, 12);
    mqf_gemm_kernel<<<gg, 256, 0, stream>>>(Wbf, XT, bq, bk, bv, projN, projT);
    dim3 ga(CN / 64, CB * CH, 3);
    mqf_attn_kernel<<<ga, 256, 0, stream>>>(projN, projT, rh, rw, outp);
}